// Round 5
// baseline (630.433 us; speedup 1.0000x reference)
//
#include <hip/hip_runtime.h>

#define NTOP 256

typedef __attribute__((ext_vector_type(8))) short bf16x8;
typedef __attribute__((ext_vector_type(4))) float f32x4;

// round-to-nearest-even split of fp32 into bf16 hi/lo, packed (hi<<16)|lo
__device__ inline unsigned int packbf(float x) {
  unsigned int u = __float_as_uint(x);
  unsigned int r = (u + 0x7fffu + ((u >> 16) & 1u)) & 0xffff0000u;
  float res = x - __uint_as_float(r);
  unsigned int u2 = __float_as_uint(res);
  unsigned int r2 = u2 + 0x7fffu + ((u2 >> 16) & 1u);
  return r | (r2 >> 16);
}

__device__ inline float tanh_fast(float x) {
  float e = __expf(2.f * x);
  return 1.f - 2.f / (e + 1.f);
}

template <int CTRL>
__device__ inline float dpp_f(float v) {
  return __int_as_float(__builtin_amdgcn_update_dpp(
      0, __float_as_int(v), CTRL, 0xf, 0xf, true));
}

// inclusive prefix sum within each 16-lane row
__device__ inline float scan16(float v) {
  float s = v;
  s += dpp_f<0x111>(s);  // row_shr:1
  s += dpp_f<0x112>(s);  // row_shr:2
  s += dpp_f<0x114>(s);  // row_shr:4
  s += dpp_f<0x118>(s);  // row_shr:8
  return s;
}

__device__ inline void gload16(const void* g, void* l) {
  __builtin_amdgcn_global_load_lds(
      (const __attribute__((address_space(1))) unsigned int*)g,
      (__attribute__((address_space(3))) unsigned int*)l, 16, 0, 0);
}

// ---------------------------------------------------------------- K1
// R1 skeleton (512 thr, j = tid>>1, k-half per thread, float4 w[32] in
// regs, 1 barrier/step) + 4 independent FMA chains + tanh_fast + DPP
// pair-reduce. Exports H pre-split as bf16 hi/lo chunk images shaped
// exactly like K2's B LDS tile: chunk kc (32 KB) = hi[256][32] | lo[256][32],
// row s = H row, col = topic j in [32kc, 32kc+32). Row 255 zeroed.
__global__ __launch_bounds__(512) void rsbc_recur(
    const float* __restrict__ Wih, const float* __restrict__ Whh,
    const float* __restrict__ bih, const float* __restrict__ bhh,
    const float* __restrict__ h0, ushort* __restrict__ Hws) {
  __shared__ float hA[NTOP], hB[NTOP];
  const int tid = threadIdx.x;
  const int j = tid >> 1, half = tid & 1, k0 = half << 7;
  const float bj = bih[j] + bhh[j];
  const int kc = j >> 5, jin = j & 31;
  const int hibase = kc * 16384 + jin;       // ushort index

  float4 w[32];
  {
    const float4* wp = reinterpret_cast<const float4*>(Wih + j * NTOP + k0);
#pragma unroll
    for (int q = 0; q < 32; ++q) w[q] = wp[q];
  }
  if (tid < NTOP) {
    hA[tid] = h0[tid];
    // zero row 255 of each chunk image (tid -> (chunk, col))
    int zc = tid >> 5, zj = tid & 31;
    Hws[zc * 16384 + 255 * 32 + zj] = 0;
    Hws[zc * 16384 + 8192 + 255 * 32 + zj] = 0;
  }
  __syncthreads();

  // step 0: h1 = tanh(h0 @ Wih^T + b)
  {
    const float* hq = hA + k0;
    float a0 = 0.f, a1 = 0.f, a2 = 0.f, a3 = 0.f;
#pragma unroll
    for (int q = 0; q < 32; ++q) {
      float4 hv = *reinterpret_cast<const float4*>(hq + 4 * q);
      a0 = fmaf(hv.x, w[q].x, a0);
      a1 = fmaf(hv.y, w[q].y, a1);
      a2 = fmaf(hv.z, w[q].z, a2);
      a3 = fmaf(hv.w, w[q].w, a3);
    }
    float sv = (a0 + a1) + (a2 + a3);
    sv += dpp_f<0xB1>(sv);               // + value from lane^1
    if (half == 0) {
      float v = tanh_fast(sv + bj);
      hB[j] = v;
      unsigned int p = packbf(v);
      Hws[hibase] = (ushort)(p >> 16);            // row 0
      Hws[hibase + 8192] = (ushort)(p & 0xffff);
    }
  }
  // Wc = W_ih + W_hh
  {
    const float4* wq = reinterpret_cast<const float4*>(Whh + j * NTOP + k0);
#pragma unroll
    for (int q = 0; q < 32; ++q) {
      float4 t = wq[q];
      w[q].x += t.x; w[q].y += t.y; w[q].z += t.z; w[q].w += t.w;
    }
  }
  __syncthreads();

#pragma unroll 1
  for (int s = 1; s < 255; ++s) {
    const float* hr = (s & 1) ? hB : hA;
    float* hw = (s & 1) ? hA : hB;
    const float* hq = hr + k0;
    float a0 = 0.f, a1 = 0.f, a2 = 0.f, a3 = 0.f;
#pragma unroll
    for (int q = 0; q < 32; ++q) {
      float4 hv = *reinterpret_cast<const float4*>(hq + 4 * q);
      a0 = fmaf(hv.x, w[q].x, a0);
      a1 = fmaf(hv.y, w[q].y, a1);
      a2 = fmaf(hv.z, w[q].z, a2);
      a3 = fmaf(hv.w, w[q].w, a3);
    }
    float sv = (a0 + a1) + (a2 + a3);
    sv += dpp_f<0xB1>(sv);
    if (half == 0) {
      float v = tanh_fast(sv + bj);
      hw[j] = v;
      unsigned int p = packbf(v);
      Hws[hibase + s * 32] = (ushort)(p >> 16);
      Hws[hibase + 8192 + s * 32] = (ushort)(p & 0xffff);
    }
    __syncthreads();
  }
}

// ---------------------------------------------------------------- K2
// bf16x3 MFMA GEMM (Z @ H^T) + log-space stick-breaking.
// 512 thr (8 waves 2x4), BM=128, N=256, K-chunk=32 (8 chunks).
// B staged via global_load_lds (32 KB linear copy of K1's chunk image).
// A: z reg-prefetch -> bf16 hi/lo split -> LDS [128][32] x2 (16 KB).
// Epilogue: softplus + DPP scan16 + rowT fixup in regs; stores staged
// through LDS in 32-row slices for full-cacheline float4 writes.
__global__ __launch_bounds__(512) void rsbc_gemm_sb(
    const float* __restrict__ z, const ushort* __restrict__ Hws,
    float* __restrict__ out) {
  __shared__ __align__(16) char smem[49152];
  __shared__ float rowT[128 * 5];
  char* Ab = smem;            // A: hi 8 KB | lo 8 KB
  char* Bb = smem + 16384;    // B: hi 16 KB | lo 16 KB

  const int tid = threadIdx.x;
  const size_t row0 = (size_t)blockIdx.x * 128;
  const int wid = tid >> 6, lane = tid & 63;
  const int wr = wid >> 2, wc = wid & 3;
  const int l15 = lane & 15, l4 = lane >> 4;

  f32x4 acc[4][4];
#pragma unroll
  for (int mt = 0; mt < 4; ++mt)
#pragma unroll
    for (int nt = 0; nt < 4; ++nt) acc[mt][nt] = (f32x4){0.f, 0.f, 0.f, 0.f};

  // prefetch z chunk 0
  float4 zpre[2];
#pragma unroll
  for (int it = 0; it < 2; ++it) {
    int idx = tid + 512 * it;
    int r = idx >> 3, q = idx & 7;
    zpre[it] = *reinterpret_cast<const float4*>(z + (row0 + r) * NTOP + 4 * q);
  }

  for (int kc = 0; kc < 8; ++kc) {
    __syncthreads();                  // prev chunk frag reads done
    // ---- A: convert prefetched z, write hi/lo planes
#pragma unroll
    for (int it = 0; it < 2; ++it) {
      int idx = tid + 512 * it;
      int r = idx >> 3, q = idx & 7;
      float4 v = zpre[it];
      unsigned int p0 = packbf(v.x), p1 = packbf(v.y),
                   p2 = packbf(v.z), p3 = packbf(v.w);
      *reinterpret_cast<ushort4*>(Ab + r * 64 + 8 * q) =
          make_ushort4((ushort)(p0 >> 16), (ushort)(p1 >> 16),
                       (ushort)(p2 >> 16), (ushort)(p3 >> 16));
      *reinterpret_cast<ushort4*>(Ab + 8192 + r * 64 + 8 * q) =
          make_ushort4((ushort)(p0 & 0xffff), (ushort)(p1 & 0xffff),
                       (ushort)(p2 & 0xffff), (ushort)(p3 & 0xffff));
    }
    // ---- B: async linear copy of 32 KB chunk image (no regs, no VALU)
    {
      const char* src = reinterpret_cast<const char*>(Hws) + kc * 32768;
#pragma unroll
      for (int it = 0; it < 4; ++it) {
        int off = (tid + 512 * it) * 16;
        gload16(src + off, Bb + off);
      }
    }
    // ---- prefetch next z chunk (latency spans MFMA phase)
    if (kc < 7) {
#pragma unroll
      for (int it = 0; it < 2; ++it) {
        int idx = tid + 512 * it;
        int r = idx >> 3, q = idx & 7;
        zpre[it] = *reinterpret_cast<const float4*>(
            z + (row0 + r) * NTOP + (kc + 1) * 32 + 4 * q);
      }
    }
    __syncthreads();                  // staged (incl. vmcnt drain)
    // ---- 48 MFMA (K=32), mt in pairs to cap register pressure
#pragma unroll
    for (int mtp = 0; mtp < 2; ++mtp) {
      bf16x8 ah[2], al[2];
#pragma unroll
      for (int m = 0; m < 2; ++m) {
        int r = 64 * wr + 16 * (2 * mtp + m) + l15;
        ah[m] = *reinterpret_cast<const bf16x8*>(Ab + r * 64 + l4 * 16);
        al[m] = *reinterpret_cast<const bf16x8*>(Ab + 8192 + r * 64 + l4 * 16);
      }
#pragma unroll
      for (int nt = 0; nt < 4; ++nt) {
        int n = 64 * wc + 16 * nt + l15;
        bf16x8 bh = *reinterpret_cast<const bf16x8*>(Bb + n * 64 + l4 * 16);
        bf16x8 bl =
            *reinterpret_cast<const bf16x8*>(Bb + 16384 + n * 64 + l4 * 16);
#pragma unroll
        for (int m = 0; m < 2; ++m) {
          int mt = 2 * mtp + m;
          acc[mt][nt] = __builtin_amdgcn_mfma_f32_16x16x32_bf16(
              ah[m], bh, acc[mt][nt], 0, 0, 0);
          acc[mt][nt] = __builtin_amdgcn_mfma_f32_16x16x32_bf16(
              ah[m], bl, acc[mt][nt], 0, 0, 0);
          acc[mt][nt] = __builtin_amdgcn_mfma_f32_16x16x32_bf16(
              al[m], bh, acc[mt][nt], 0, 0, 0);
        }
      }
    }
  }

  // ---- epilogue pass A: zc, sp=softplus, in-register prefix scan
  // C layout: row = 64wr+16mt+4*l4+i, col = 64wc+16nt+l15
  float lt[4];
#pragma unroll
  for (int nt = 0; nt < 4; ++nt) {
    int col = 64 * wc + 16 * nt + l15;
    lt[nt] = (col < 255) ? __logf((float)(255 - col)) : 0.f;
  }
#pragma unroll
  for (int mt = 0; mt < 4; ++mt)
#pragma unroll
    for (int i = 0; i < 4; ++i) {
      float carry = 0.f;
#pragma unroll
      for (int nt = 0; nt < 4; ++nt) {
        float a = acc[mt][nt][i];
        float t1 = __expf(-a);
        float s1 = __builtin_amdgcn_rcpf(1.f + t1);   // sigmoid(logit)
        float x = s1 - lt[nt];
        float t = __expf(-x);
        float zc = __builtin_amdgcn_rcpf(1.f + t);    // sigmoid(x)
        float sp = x + __logf(1.f + t);               // softplus(x)
        if ((wc == 3) && (nt == 3) && (l15 == 15)) {  // col 255 dummy
          zc = 1.f; sp = 0.f;
        }
        float incl = scan16(sp);
        float Sl = carry + (incl - sp);               // exclusive prefix
        acc[mt][nt][i] = zc * __expf(-Sl);
        carry += __shfl(incl, 15, 16);
      }
      if (l15 == 0)
        rowT[(64 * wr + 16 * mt + 4 * l4 + i) * 5 + wc] = carry;
    }
  __syncthreads();   // rowT visible; staging LDS now dead -> reuse

  // ---- pass B: cross-wave offset, slice-staged full-line stores
  float* stage = reinterpret_cast<float*>(smem);      // [32][260] = 33 KB
#pragma unroll 1
  for (int mt = 0; mt < 4; ++mt) {
#pragma unroll
    for (int i = 0; i < 4; ++i) {
      int rl = 16 * wr + 4 * l4 + i;                  // row within slice
      int r = 64 * wr + 16 * mt + 4 * l4 + i;
      float ew = 1.f;
      if (wc > 0) {
        float W = rowT[r * 5 + 0];
        if (wc > 1) W += rowT[r * 5 + 1];
        if (wc > 2) W += rowT[r * 5 + 2];
        ew = __expf(-W);
      }
#pragma unroll
      for (int nt = 0; nt < 4; ++nt)
        stage[rl * 260 + 64 * wc + 16 * nt + l15] = acc[mt][nt][i] * ew;
    }
    __syncthreads();
#pragma unroll
    for (int it = 0; it < 4; ++it) {
      int idx = tid + 512 * it;        // 0..2047
      int rr = idx >> 6, cq = idx & 63;
      int grow = 64 * (rr >> 4) + 16 * mt + (rr & 15);
      float4 v4 = *reinterpret_cast<const float4*>(stage + rr * 260 + 4 * cq);
      *reinterpret_cast<float4*>(&out[(row0 + grow) * NTOP + 4 * cq]) = v4;
    }
    __syncthreads();
  }
}

// ---------------------------------------------------------------- launch
extern "C" void kernel_launch(void* const* d_in, const int* in_sizes, int n_in,
                              void* d_out, int out_size, void* d_ws, size_t ws_size,
                              hipStream_t stream) {
  const float* z   = (const float*)d_in[0];
  const float* h0  = (const float*)d_in[1];
  const float* Wih = (const float*)d_in[2];
  const float* Whh = (const float*)d_in[3];
  const float* bih = (const float*)d_in[4];
  const float* bhh = (const float*)d_in[5];
  float* out = (float*)d_out;
  ushort* Hws = (ushort*)d_ws;   // 8 chunks x 32 KB = 256 KB

  rsbc_recur<<<1, 512, 0, stream>>>(Wih, Whh, bih, bhh, h0, Hws);
  const int nrows = out_size / NTOP;   // 131072
  const int blocks = nrows / 128;      // 1024
  rsbc_gemm_sb<<<blocks, 512, 0, stream>>>(z, Hws, out);
}